// Round 5
// baseline (170.900 us; speedup 1.0000x reference)
//
#include <hip/hip_runtime.h>

#define ALPHA 0.2f

constexpr int BB  = 4;
constexpr int NN  = 2048;
constexpr int FIN = 128;
constexpr int FO  = 64;
constexpr int HH  = 4;
constexpr int CC  = BB * HH;   // 16 (b,h) combos

using half8   = __attribute__((ext_vector_type(8))) _Float16;
using fp16x2  = __attribute__((ext_vector_type(2))) __fp16;   // cvt_pkrtz return type
using floatx4 = __attribute__((ext_vector_type(4))) float;

union H8 { half8 v; fp16x2 h[4]; };
union H2U { fp16x2 h; unsigned u; };

__device__ __forceinline__ float fexp2(float x) {
#if __has_builtin(__builtin_amdgcn_exp2f)
  return __builtin_amdgcn_exp2f(x);
#else
  return __expf(x * 0.69314718055994531f);
#endif
}

// monotone float<->uint key for atomicMax over possibly-negative floats
__device__ __forceinline__ unsigned fkey(float f) {
  unsigned b = __float_as_uint(f);
  return (b & 0x80000000u) ? ~b : (b | 0x80000000u);
}
__device__ __forceinline__ float funkey(unsigned k) {
  return __uint_as_float((k & 0x80000000u) ? (k & 0x7fffffffu) : ~k);
}

// ---------------------------------------------------------------------------
// K0: blocks 0..511 bitpack adj (16 MB HBM stream, read once);
//     block 512: W -> WT[h][col][k] f16 transpose + gmax key init.
// ---------------------------------------------------------------------------
__global__ __launch_bounds__(256) void gat_k0(
    const float* __restrict__ adj, const float* __restrict__ W,
    unsigned* __restrict__ adjbits, _Float16* __restrict__ WT,
    unsigned* __restrict__ gmaxkey) {
  const int blk = blockIdx.x, t = threadIdx.x;
  __shared__ __align__(16) float L[128 * 68];   // 34.8 KB (only block 512 uses)

  if (blk < 512) {
    const int w = t >> 6, l = t & 63;
    const int m = blk * 4 + w;
    const float* arow = adj + (size_t)m * NN;
    float areg[32];
#pragma unroll
    for (int j = 0; j < 32; ++j) areg[j] = arow[j * 64 + l];
#pragma unroll
    for (int j = 0; j < 32; ++j) {
      const unsigned long long mask = __ballot(areg[j] != 0.f);
      if (l == 0) {
        adjbits[m * 64 + 2 * j + 0] = (unsigned)mask;
        adjbits[m * 64 + 2 * j + 1] = (unsigned)(mask >> 32);
      }
    }
  } else {
    if (t < CC) gmaxkey[t] = 0u;   // 0 < fkey(f) for all finite f
    for (int hh = 0; hh < HH; ++hh) {
      __syncthreads();
      const float4* Wg = (const float4*)(W + (size_t)hh * FIN * FO);
#pragma unroll
      for (int r = 0; r < 8; ++r) {
        const int fidx = t + r * 256;            // 0..2047 float4s of W[hh]
        const int k = fidx >> 4, c4 = fidx & 15;
        *(float4*)&L[k * 68 + c4 * 4] = Wg[fidx];
      }
      __syncthreads();
      const int col = t & 63, kb = (t >> 6) * 32;
      _Float16* dst = WT + ((size_t)(hh * FO + col)) * FIN + kb;
#pragma unroll
      for (int kk = 0; kk < 32; ++kk) dst[kk] = (_Float16)L[(kb + kk) * 68 + col];
    }
  }
}

// ---------------------------------------------------------------------------
// K1: projection via f16 MFMA, LDS-free & barrier-free. Block = 32 nodes,
// wave = head. Emits htT[c][f][n] f16, esrc/edst (pre-scaled by log2e),
// and gmax[c] via atomicMax. grid 256 x 256.
// ---------------------------------------------------------------------------
__global__ __launch_bounds__(256) void gat_k1(
    const float* __restrict__ h, const _Float16* __restrict__ WT,
    const float* __restrict__ a, _Float16* __restrict__ htT,
    float* __restrict__ esrc, float* __restrict__ edst,
    unsigned* __restrict__ gmaxkey) {
  const int blk = blockIdx.x;
  const int b = blk >> 6;
  const int nb = (blk & 63) * 32;    // node base within batch
  const int t = threadIdx.x;
  const int hh = t >> 6, lane = t & 63;
  const int q = lane >> 4, r16 = lane & 15;
  const int c = b * HH + hh;
  const float* hbase = h + ((size_t)(b * NN + nb)) * FIN;
  const _Float16* wbase = WT + (size_t)hh * FO * FIN;

  floatx4 acc[2][4];
#pragma unroll
  for (int rg = 0; rg < 2; ++rg)
#pragma unroll
    for (int ft = 0; ft < 4; ++ft) acc[rg][ft] = floatx4{0.f, 0.f, 0.f, 0.f};

#pragma unroll
  for (int kk = 0; kk < 4; ++kk) {
    // A-frags: lane -> A[row=r16][k=q*8+j]; rows rg*16+r16
    half8 afr[2];
#pragma unroll
    for (int rg = 0; rg < 2; ++rg) {
      const float* xp = hbase + (size_t)(rg * 16 + r16) * FIN + kk * 32 + q * 8;
      const float4 x0 = *(const float4*)xp;
      const float4 x1 = *(const float4*)(xp + 4);
      H8 u;
      u.h[0] = __builtin_amdgcn_cvt_pkrtz(x0.x, x0.y);
      u.h[1] = __builtin_amdgcn_cvt_pkrtz(x0.z, x0.w);
      u.h[2] = __builtin_amdgcn_cvt_pkrtz(x1.x, x1.y);
      u.h[3] = __builtin_amdgcn_cvt_pkrtz(x1.z, x1.w);
      afr[rg] = u.v;
    }
#pragma unroll
    for (int ft = 0; ft < 4; ++ft) {
      // B-frag: lane -> B[k=q*8+j][col=r16], contiguous in WT[col][k]
      const half8 bfr =
          *(const half8*)(wbase + (size_t)(ft * 16 + r16) * FIN + kk * 32 + q * 8);
      acc[0][ft] = __builtin_amdgcn_mfma_f32_16x16x32_f16(afr[0], bfr, acc[0][ft], 0, 0, 0);
      acc[1][ft] = __builtin_amdgcn_mfma_f32_16x16x32_f16(afr[1], bfr, acc[1][ft], 0, 0, 0);
    }
  }

  // ---- esrc/edst (scaled by log2e) + gmax. D rows = q*4+x, D cols = ft*16+r16.
  const float L2E = 1.44269504f;
  float asv[4], adv[4];
#pragma unroll
  for (int ft = 0; ft < 4; ++ft) {
    asv[ft] = a[hh * 128 + ft * 16 + r16] * L2E;
    adv[ft] = a[hh * 128 + 64 + ft * 16 + r16] * L2E;
  }
  float edmax = -3.0e38f;
#pragma unroll
  for (int rg = 0; rg < 2; ++rg) {
#pragma unroll
    for (int x = 0; x < 4; ++x) {
      float es = 0.f, ed = 0.f;
#pragma unroll
      for (int ft = 0; ft < 4; ++ft) {
        es = fmaf(acc[rg][ft][x], asv[ft], es);
        ed = fmaf(acc[rg][ft][x], adv[ft], ed);
      }
#pragma unroll
      for (int off = 1; off < 16; off <<= 1) {   // allreduce over r16 lanes
        es += __shfl_xor(es, off, 64);
        ed += __shfl_xor(ed, off, 64);
      }
      if (r16 == 0) {
        const int n = nb + rg * 16 + q * 4 + x;
        esrc[c * NN + n] = es;
        edst[c * NN + n] = ed;
      }
      edmax = fmaxf(edmax, ed);   // ed identical across r16 lanes
    }
  }
  edmax = fmaxf(edmax, __shfl_xor(edmax, 16, 64));
  edmax = fmaxf(edmax, __shfl_xor(edmax, 32, 64));
  if (lane == 0) atomicMax(gmaxkey + c, fkey(edmax));

  // ---- htT store: htT[c][f][n], 4 consecutive n per (rg,ft) as 8 B
#pragma unroll
  for (int rg = 0; rg < 2; ++rg) {
#pragma unroll
    for (int ft = 0; ft < 4; ++ft) {
      H2U lo, hi;
      lo.h = __builtin_amdgcn_cvt_pkrtz(acc[rg][ft][0], acc[rg][ft][1]);
      hi.h = __builtin_amdgcn_cvt_pkrtz(acc[rg][ft][2], acc[rg][ft][3]);
      uint2 val;
      val.x = lo.u;
      val.y = hi.u;
      *(uint2*)&htT[((size_t)(c * FO + ft * 16 + r16)) * NN + nb + rg * 16 + q * 4] = val;
    }
  }
}

// ---------------------------------------------------------------------------
// K3: O = softmax(P)·V. Zero LDS, zero barriers. P built in A-frag registers;
// V B-frags loaded straight from global htT; psum via ones-MFMA (rowsums land
// in C-layout lanes). grid 512 x 256 (c x 64-row m-tile).
// ---------------------------------------------------------------------------
__global__ __launch_bounds__(256) void gat_k3(
    const _Float16* __restrict__ htT, const float* __restrict__ esrc,
    const float* __restrict__ edst, const unsigned* __restrict__ adjbits,
    const unsigned* __restrict__ gmaxkey, float* __restrict__ out) {
  const int blk = blockIdx.x;
  const int c = blk >> 5;
  const int m0 = (blk & 31) * 64;
  const int b = c >> 2, hh = c & 3;
  const int t = threadIdx.x;
  const int w = t >> 6, lane = t & 63;
  const int q = lane >> 4, r16 = lane & 15;
  const int row = m0 + w * 16 + r16;    // this thread's A-fragment row

  const float em = esrc[c * NN + row];
  const float gm = funkey(gmaxkey[c]);
  const float sm = em + gm;
  const float rm = fmaxf(sm, ALPHA * sm);   // lrelu(em+gmax) >= all masked scores
  const float emr = em - rm;                // s - rm = emr + ed
  const float em2 = fmaf(ALPHA, em, -rm);   // 0.2s - rm = em2 + 0.2*ed
  const float* edc = edst + (size_t)c * NN;
  const unsigned* abrow = adjbits + (size_t)row * 64;
  const _Float16* vsrc = htT + (size_t)c * FO * NN;

  half8 ones;
#pragma unroll
  for (int j = 0; j < 8; ++j) ones[j] = (_Float16)1.0f;

  floatx4 acc[4], accp;
#pragma unroll
  for (int ft = 0; ft < 4; ++ft) acc[ft] = floatx4{0.f, 0.f, 0.f, 0.f};
  accp = floatx4{0.f, 0.f, 0.f, 0.f};

  for (int it = 0; it < 32; ++it) {
    const int n0 = it * 64;
    const uint2 bw = *(const uint2*)(abrow + it * 2);
    // ---- build A-fragments: p = exp2(lrelu-score - rm), masked
    half8 af[2];
#pragma unroll
    for (int kk2 = 0; kk2 < 2; ++kk2) {
      const float* edp = edc + n0 + kk2 * 32 + q * 8;
      const float4 e0 = *(const float4*)edp;
      const float4 e1 = *(const float4*)(edp + 4);
      const float xs[8] = {e0.x, e0.y, e0.z, e0.w, e1.x, e1.y, e1.z, e1.w};
      const unsigned bits = ((kk2 == 0) ? bw.x : bw.y) >> (q * 8);
      H8 u;
#pragma unroll
      for (int jp = 0; jp < 4; ++jp) {
        float p[2];
#pragma unroll
        for (int k = 0; k < 2; ++k) {
          const int j = jp * 2 + k;
          const float x = fmaxf(emr + xs[j], fmaf(ALPHA, xs[j], em2));
          float pv = fexp2(x);
          p[k] = ((bits >> j) & 1u) ? pv : 0.f;
        }
        u.h[jp] = __builtin_amdgcn_cvt_pkrtz(p[0], p[1]);
      }
      af[kk2] = u.v;
    }
    // ---- MFMAs: 4 ft + 1 ones (rowsum) per kk2
#pragma unroll
    for (int kk2 = 0; kk2 < 2; ++kk2) {
      accp = __builtin_amdgcn_mfma_f32_16x16x32_f16(af[kk2], ones, accp, 0, 0, 0);
#pragma unroll
      for (int ft = 0; ft < 4; ++ft) {
        const half8 bfr = *(const half8*)(vsrc + (size_t)(ft * 16 + r16) * NN +
                                          n0 + kk2 * 32 + q * 8);
        acc[ft] = __builtin_amdgcn_mfma_f32_16x16x32_f16(af[kk2], bfr, acc[ft], 0, 0, 0);
      }
    }
  }

  // ---- epilogue: accp[x] = rowsum(q*4+x), already in the right lanes
#pragma unroll
  for (int x = 0; x < 4; ++x) {
    const float rinv = 1.0f / accp[x];
    const int mrow = m0 + w * 16 + q * 4 + x;
    float* op = out + ((size_t)b * NN + mrow) * 256 + hh * 64;
#pragma unroll
    for (int ft = 0; ft < 4; ++ft) op[ft * 16 + r16] = acc[ft][x] * rinv;
  }
}

// ---------------------------------------------------------------------------
extern "C" void kernel_launch(void* const* d_in, const int* in_sizes, int n_in,
                              void* d_out, int out_size, void* d_ws, size_t ws_size,
                              hipStream_t stream) {
  const float* h   = (const float*)d_in[0];   // (4,2048,128)
  const float* adj = (const float*)d_in[1];   // (2048,2048)
  const float* W   = (const float*)d_in[2];   // (4,128,64)
  const float* a   = (const float*)d_in[3];   // (4,128,1)
  float* out = (float*)d_out;                  // (4,2048,256)

  char* ws = (char*)d_ws;
  _Float16* htT     = (_Float16*)(ws);                             // 4 MB
  float* esrc       = (float*)(ws + 4 * 1024 * 1024);              // 128 KB
  float* edst       = (float*)(ws + 4 * 1024 * 1024 + 131072);     // 128 KB
  unsigned* abits   = (unsigned*)(ws + 4 * 1024 * 1024 + 262144);  // 512 KB
  _Float16* WT      = (_Float16*)(ws + 4 * 1024 * 1024 + 262144 + 524288);  // 64 KB
  unsigned* gmaxkey = (unsigned*)(ws + 4 * 1024 * 1024 + 262144 + 524288 + 65536);  // 64 B

  gat_k0<<<dim3(513), dim3(256), 0, stream>>>(adj, W, abits, WT, gmaxkey);
  gat_k1<<<dim3(256), dim3(256), 0, stream>>>(h, WT, a, htT, esrc, edst, gmaxkey);
  gat_k3<<<dim3(512), dim3(256), 0, stream>>>(htT, esrc, edst, abits, gmaxkey, out);
}